// Round 1
// baseline (412.089 us; speedup 1.0000x reference)
//
#include <hip/hip_runtime.h>
#include <math.h>

#define DIMC 128
#define HEADSC 4

// ---------------- GEMM: h = x @ W, fused a_s/a_d epilogue ----------------
// Thread t owns output column c=t. W column cached in 128 VGPRs (full k-unroll).
// x row elements are wave-uniform -> compiler emits scalar loads.
__global__ __launch_bounds__(128) void gemm_kernel(
    const float* __restrict__ x, const float* __restrict__ W,
    const float* __restrict__ att_src, const float* __restrict__ att_dst,
    float* __restrict__ h, float* __restrict__ a_s, float* __restrict__ a_d,
    int N, int rows_per_block)
{
    const int c = threadIdx.x;              // 0..127 output column
    const int row0 = blockIdx.x * rows_per_block;
    float wreg[DIMC];
#pragma unroll
    for (int k = 0; k < DIMC; ++k) wreg[k] = W[k * DIMC + c];
    const float attS = att_src[c];          // att_src is [4][32] flat = 128
    const float attD = att_dst[c];
    const int rend = (row0 + rows_per_block < N) ? (row0 + rows_per_block) : N;
    for (int row = row0; row < rend; ++row) {
        const float* __restrict__ xr = x + (size_t)row * DIMC;
        float a0 = 0.f, a1 = 0.f, a2 = 0.f, a3 = 0.f;
#pragma unroll
        for (int k = 0; k < DIMC; k += 4) {
            a0 = fmaf(xr[k + 0], wreg[k + 0], a0);
            a1 = fmaf(xr[k + 1], wreg[k + 1], a1);
            a2 = fmaf(xr[k + 2], wreg[k + 2], a2);
            a3 = fmaf(xr[k + 3], wreg[k + 3], a3);
        }
        float acc = (a0 + a1) + (a2 + a3);
        h[(size_t)row * DIMC + c] = acc;
        // per-head (32-lane) reductions for attention logits
        float ps = acc * attS;
        float pd = acc * attD;
#pragma unroll
        for (int m = 1; m < 32; m <<= 1) {
            ps += __shfl_xor(ps, m);
            pd += __shfl_xor(pd, m);
        }
        if ((c & 31) == 0) {
            a_s[row * HEADSC + (c >> 5)] = ps;
            a_d[row * HEADSC + (c >> 5)] = pd;
        }
    }
}

// ---------------- in-degree histogram (edges only) ----------------
__global__ void hist_kernel(const int* __restrict__ dst, int E,
                            int* __restrict__ counts)
{
    int i = blockIdx.x * blockDim.x + threadIdx.x;
    int stride = gridDim.x * blockDim.x;
    for (; i < E; i += stride) atomicAdd(&counts[dst[i]], 1);
}

// ---------------- exclusive scan over counts+1 (self loop) ----------------
__global__ __launch_bounds__(1024) void scan_kernel(
    const int* __restrict__ counts, int* __restrict__ offsets,
    int* __restrict__ cursor, int N)
{
    __shared__ int wsum[16];
    __shared__ int chunk_total;
    __shared__ int carry_s;
    const int tid = threadIdx.x;
    if (tid == 0) carry_s = 0;
    __syncthreads();
    for (int base = 0; base < N; base += 1024) {
        const int i = base + tid;
        const int v = (i < N) ? (counts[i] + 1) : 0;   // +1 = self loop
        const int lane = tid & 63, wv = tid >> 6;
        int xs = v;
#pragma unroll
        for (int d = 1; d < 64; d <<= 1) {
            int tt = __shfl_up(xs, d);
            if (lane >= d) xs += tt;
        }
        if (lane == 63) wsum[wv] = xs;
        __syncthreads();
        if (tid == 0) {
            int s = 0;
            for (int w2 = 0; w2 < 16; ++w2) { int tt = wsum[w2]; wsum[w2] = s; s += tt; }
            chunk_total = s;
        }
        __syncthreads();
        const int excl = carry_s + wsum[wv] + xs - v;
        if (i < N) { offsets[i] = excl; cursor[i] = excl; }
        __syncthreads();
        if (tid == 0) carry_s += chunk_total;
        __syncthreads();
    }
    if (tid == 0) offsets[N] = carry_s;
}

// ---------------- CSR scatter (edges + self loops) ----------------
__global__ void scatter_kernel(const int* __restrict__ ei, int E, int N,
                               int* __restrict__ cursor, int* __restrict__ rec)
{
    int i = blockIdx.x * blockDim.x + threadIdx.x;
    const int total = E + N;
    const int stride = gridDim.x * blockDim.x;
    for (; i < total; i += stride) {
        int s, d;
        if (i < E) { s = ei[i]; d = ei[E + i]; }
        else       { s = i - E; d = s; }
        const int pos = atomicAdd(&cursor[d], 1);
        rec[pos] = s;
    }
}

// ---------------- per-node: online softmax agg + bias + GELU + LN ----------------
__global__ __launch_bounds__(128) void node_kernel(
    const float* __restrict__ x, const float* __restrict__ h,
    const float* __restrict__ a_s, const float* __restrict__ a_d,
    const int* __restrict__ offsets, const int* __restrict__ rec,
    const float* __restrict__ bias, const float* __restrict__ gamma,
    const float* __restrict__ beta, float* __restrict__ out, int N)
{
    const int n = blockIdx.x;
    const int t = threadIdx.x;          // channel 0..127
    const int head = t >> 5;
    const float adh = a_d[n * HEADSC + head];
    const int beg = offsets[n], end = offsets[n + 1];
    float m = -INFINITY, den = 0.f, acc = 0.f;
    for (int i = beg; i < end; ++i) {
        const int s = rec[i];
        float e = a_s[s * HEADSC + head] + adh;
        e = (e > 0.f) ? e : 0.2f * e;                  // leaky relu
        const float hv = h[(size_t)s * DIMC + t];
        if (e <= m) {
            const float p = __expf(e - m);
            den += p;
            acc = fmaf(p, hv, acc);
        } else {
            const float sc = __expf(m - e);            // exp(-inf)=0 on first iter
            den = fmaf(den, sc, 1.f);
            acc = fmaf(acc, sc, hv);
            m = e;
        }
    }
    float g = acc / (den + 1e-16f) + bias[t];
    // exact erf GELU
    const float ge = 0.5f * g * (1.f + erff(g * 0.70710678118654752f));
    const float y = x[(size_t)n * DIMC + t] + ge;
    // block LayerNorm over 128 channels
    float s1 = y, s2 = y * y;
#pragma unroll
    for (int mm = 1; mm < 64; mm <<= 1) {
        s1 += __shfl_xor(s1, mm);
        s2 += __shfl_xor(s2, mm);
    }
    __shared__ float ws1[2], ws2[2];
    const int wv = t >> 6;
    if ((t & 63) == 0) { ws1[wv] = s1; ws2[wv] = s2; }
    __syncthreads();
    const float S1 = ws1[0] + ws1[1];
    const float S2 = ws2[0] + ws2[1];
    const float mu = S1 * (1.f / DIMC);
    const float var = S2 * (1.f / DIMC) - mu * mu;
    const float rstd = rsqrtf(var + 1e-5f);
    out[(size_t)n * DIMC + t] = (y - mu) * rstd * gamma[t] + beta[t];
}

extern "C" void kernel_launch(void* const* d_in, const int* in_sizes, int n_in,
                              void* d_out, int out_size, void* d_ws, size_t ws_size,
                              hipStream_t stream)
{
    const float* x       = (const float*)d_in[0];
    const float* W       = (const float*)d_in[1];
    const float* bias    = (const float*)d_in[2];
    const float* att_src = (const float*)d_in[3];
    const float* att_dst = (const float*)d_in[4];
    const float* gamma   = (const float*)d_in[5];
    const float* beta    = (const float*)d_in[6];
    const int*   ei      = (const int*)d_in[7];   // [2][E]: row0=src, row1=dst

    const int N = in_sizes[0] / DIMC;
    const int E = in_sizes[7] / 2;

    // workspace layout (all fp32/int32, 4B-aligned)
    float* h    = (float*)d_ws;                       // N*128
    float* a_s  = h + (size_t)N * DIMC;               // N*4
    float* a_d  = a_s + (size_t)N * HEADSC;           // N*4
    int* counts = (int*)(a_d + (size_t)N * HEADSC);   // N
    int* offsets = counts + N;                        // N+1
    int* cursor  = offsets + N + 1;                   // N
    int* rec     = cursor + N;                        // E+N

    hipMemsetAsync(counts, 0, sizeof(int) * (size_t)N, stream);

    const int RPB = 32;
    gemm_kernel<<<(N + RPB - 1) / RPB, 128, 0, stream>>>(
        x, W, att_src, att_dst, h, a_s, a_d, N, RPB);
    hist_kernel<<<1024, 256, 0, stream>>>(ei + E, E, counts);
    scan_kernel<<<1, 1024, 0, stream>>>(counts, offsets, cursor, N);
    scatter_kernel<<<1024, 256, 0, stream>>>(ei, E, N, cursor, rec);
    node_kernel<<<N, 128, 0, stream>>>(
        x, h, a_s, a_d, offsets, rec, bias, gamma, beta, (float*)d_out, N);
}

// Round 2
// 277.302 us; speedup vs baseline: 1.4861x; 1.4861x over previous
//
#include <hip/hip_runtime.h>
#include <math.h>

#define DIMC 128
#define HEADSC 4

typedef __attribute__((ext_vector_type(8))) short bf16x8;
typedef __attribute__((ext_vector_type(4))) float f32x4;

static __device__ __forceinline__ float bf2f(unsigned short u) {
    unsigned v = ((unsigned)u) << 16;
    return __builtin_bit_cast(float, v);
}
static __device__ __forceinline__ short f2bf(float f) {
    unsigned u = __builtin_bit_cast(unsigned, f);
    unsigned r = (u + 0x7fff + ((u >> 16) & 1)) >> 16;   // RNE
    return (short)r;
}

// ---------------- GEMM: h = x @ W via bf16 MFMA, h stored bf16 ----------------
// 256 threads = 4 waves = 2 wave-pairs. Each pair owns a 16-row strip; wave
// half h covers columns h*64..h*64+63 (4 col-tiles). W fragments live in 64
// VGPRs per wave (statically indexed -> register-allocated).
__global__ __launch_bounds__(256) void gemm_kernel(
    const float* __restrict__ x, const float* __restrict__ W,
    unsigned short* __restrict__ hb, int N, int nstrip)
{
    const int lane = threadIdx.x & 63;
    const int wv   = threadIdx.x >> 6;   // 0..3
    const int pr   = wv >> 1;            // strip-pair 0/1
    const int half = wv & 1;             // column half
    const int l15  = lane & 15;
    const int lg   = lane >> 4;          // 0..3

    // B fragments: B[k][j], j = l15 (+ct*16+half*64), k = kk*32 + lg*8 + jj
    bf16x8 bfr[4][4];
#pragma unroll
    for (int ct = 0; ct < 4; ++ct) {
#pragma unroll
        for (int kk = 0; kk < 4; ++kk) {
            const float* wp = W + (size_t)(kk * 32 + lg * 8) * DIMC + half * 64 + ct * 16 + l15;
#pragma unroll
            for (int jj = 0; jj < 8; ++jj)
                bfr[ct][kk][jj] = f2bf(wp[(size_t)jj * DIMC]);
        }
    }

    for (int s = blockIdx.x * 2 + pr; s < nstrip; s += gridDim.x * 2) {
        const int row = s * 16 + l15;
        const float* xp = x + (size_t)row * DIMC + lg * 8;
        bf16x8 afr[4];
#pragma unroll
        for (int kk = 0; kk < 4; ++kk) {
            f32x4 v0 = *(const f32x4*)(xp + kk * 32);
            f32x4 v1 = *(const f32x4*)(xp + kk * 32 + 4);
#pragma unroll
            for (int jj = 0; jj < 4; ++jj) {
                afr[kk][jj]     = f2bf(v0[jj]);
                afr[kk][jj + 4] = f2bf(v1[jj]);
            }
        }
        f32x4 acc[4] = {};
#pragma unroll
        for (int ct = 0; ct < 4; ++ct) {
#pragma unroll
            for (int kk = 0; kk < 4; ++kk)
                acc[ct] = __builtin_amdgcn_mfma_f32_16x16x32_bf16(
                    afr[kk], bfr[ct][kk], acc[ct], 0, 0, 0);
        }
        unsigned short* hp = hb + (size_t)(s * 16) * DIMC + half * 64;
#pragma unroll
        for (int ct = 0; ct < 4; ++ct)
#pragma unroll
            for (int reg = 0; reg < 4; ++reg)
                hp[(size_t)(lg * 4 + reg) * DIMC + ct * 16 + l15] =
                    (unsigned short)f2bf(acc[ct][reg]);
    }
}

// ---------------- per-node attention logits from bf16 h ----------------
__global__ __launch_bounds__(128) void attn_kernel(
    const unsigned short* __restrict__ hb,
    const float* __restrict__ att_src, const float* __restrict__ att_dst,
    float* __restrict__ a_s, float* __restrict__ a_d)
{
    const int n = blockIdx.x;
    const int t = threadIdx.x;
    const float hv = bf2f(hb[(size_t)n * DIMC + t]);
    float ps = hv * att_src[t];
    float pd = hv * att_dst[t];
#pragma unroll
    for (int mk = 1; mk < 32; mk <<= 1) {
        ps += __shfl_xor(ps, mk);
        pd += __shfl_xor(pd, mk);
    }
    if ((t & 31) == 0) {
        a_s[n * HEADSC + (t >> 5)] = ps;
        a_d[n * HEADSC + (t >> 5)] = pd;
    }
}

// ---------------- in-degree histogram ----------------
__global__ void hist_kernel(const int* __restrict__ dst, int E, int* __restrict__ counts)
{
    int i = blockIdx.x * blockDim.x + threadIdx.x;
    int stride = gridDim.x * blockDim.x;
    for (; i < E; i += stride) atomicAdd(&counts[dst[i]], 1);
}

// ---------------- 3-phase exclusive scan over (counts[i]+1) ----------------
__global__ __launch_bounds__(256) void scan1_kernel(
    const int* __restrict__ counts, int* __restrict__ partial, int N)
{
    const int t = threadIdx.x, i = blockIdx.x * 256 + t;
    int v = (i < N) ? counts[i] + 1 : 0;
    int s = v;
#pragma unroll
    for (int mk = 1; mk < 64; mk <<= 1) s += __shfl_xor(s, mk);
    __shared__ int ws[4];
    if ((t & 63) == 0) ws[t >> 6] = s;
    __syncthreads();
    if (t == 0) partial[blockIdx.x] = ws[0] + ws[1] + ws[2] + ws[3];
}

__global__ __launch_bounds__(256) void scan2_kernel(
    int* __restrict__ partial, int* __restrict__ offsets, int P, int N)
{
    const int t = threadIdx.x;
    const int lane = t & 63, wv = t >> 6;
    int v = (t < P) ? partial[t] : 0;
    int xs = v;
#pragma unroll
    for (int d = 1; d < 64; d <<= 1) {
        int tt = __shfl_up(xs, d);
        if (lane >= d) xs += tt;
    }
    __shared__ int ws[4], wo[4];
    if (lane == 63) ws[wv] = xs;
    __syncthreads();
    if (t == 0) {
        int s = 0;
        for (int w = 0; w < 4; ++w) { wo[w] = s; s += ws[w]; }
        offsets[N] = s;
    }
    __syncthreads();
    if (t < P) partial[t] = wo[wv] + xs - v;   // exclusive block offset
}

__global__ __launch_bounds__(256) void scan3_kernel(
    const int* __restrict__ counts, const int* __restrict__ partial,
    int* __restrict__ offsets, int* __restrict__ cursor, int N)
{
    const int t = threadIdx.x, i = blockIdx.x * 256 + t;
    const int lane = t & 63, wv = t >> 6;
    int v = (i < N) ? counts[i] + 1 : 0;
    int xs = v;
#pragma unroll
    for (int d = 1; d < 64; d <<= 1) {
        int tt = __shfl_up(xs, d);
        if (lane >= d) xs += tt;
    }
    __shared__ int ws[4], wo[4];
    if (lane == 63) ws[wv] = xs;
    __syncthreads();
    if (t == 0) {
        int s = 0;
        for (int w = 0; w < 4; ++w) { wo[w] = s; s += ws[w]; }
    }
    __syncthreads();
    const int excl = partial[blockIdx.x] + wo[wv] + xs - v;
    if (i < N) { offsets[i] = excl; cursor[i] = excl; }
}

// ---------------- CSR scatter (edges + self loops) ----------------
__global__ void scatter_kernel(const int* __restrict__ ei, int E, int N,
                               int* __restrict__ cursor, int* __restrict__ rec)
{
    int i = blockIdx.x * blockDim.x + threadIdx.x;
    const int total = E + N;
    const int stride = gridDim.x * blockDim.x;
    for (; i < total; i += stride) {
        int s, d;
        if (i < E) { s = ei[i]; d = ei[E + i]; }
        else       { s = i - E; d = s; }
        const int pos = atomicAdd(&cursor[d], 1);
        rec[pos] = s;
    }
}

// ---------------- per-node: 2-pass softmax agg + bias + GELU + LN ----------------
__global__ __launch_bounds__(128) void node_kernel(
    const float* __restrict__ x, const unsigned short* __restrict__ hb,
    const float* __restrict__ a_s, const float* __restrict__ a_d,
    const int* __restrict__ offsets, const int* __restrict__ rec,
    const float* __restrict__ bias, const float* __restrict__ gamma,
    const float* __restrict__ beta, float* __restrict__ out)
{
    const int n = blockIdx.x;
    const int t = threadIdx.x;          // channel 0..127
    const int head = t >> 5;
    const int c = t & 31;
    const float adh = a_d[n * HEADSC + head];
    const int beg = offsets[n], end = offsets[n + 1];

    // pass 1: per-head max over incoming edges (32 lanes split the edge list)
    float m = -INFINITY;
    for (int i = beg + c; i < end; i += 32) {
        float e = a_s[rec[i] * HEADSC + head] + adh;
        e = (e > 0.f) ? e : 0.2f * e;
        m = fmaxf(m, e);
    }
#pragma unroll
    for (int mk = 1; mk < 32; mk <<= 1) m = fmaxf(m, __shfl_xor(m, mk));

    // pass 2: independent-iteration accumulate (no rescale chain)
    float den = 0.f, acc = 0.f;
    for (int i = beg; i < end; ++i) {
        const int s = rec[i];
        float e = a_s[s * HEADSC + head] + adh;
        e = (e > 0.f) ? e : 0.2f * e;
        const float p = __expf(e - m);
        den += p;
        acc = fmaf(p, bf2f(hb[(size_t)s * DIMC + t]), acc);
    }

    float g = acc / (den + 1e-16f) + bias[t];
    const float ge = 0.5f * g * (1.f + erff(g * 0.70710678118654752f));
    const float y = x[(size_t)n * DIMC + t] + ge;

    float s1 = y, s2 = y * y;
#pragma unroll
    for (int mk = 1; mk < 64; mk <<= 1) {
        s1 += __shfl_xor(s1, mk);
        s2 += __shfl_xor(s2, mk);
    }
    __shared__ float ws1[2], ws2[2];
    const int wv = t >> 6;
    if ((t & 63) == 0) { ws1[wv] = s1; ws2[wv] = s2; }
    __syncthreads();
    const float S1 = ws1[0] + ws1[1];
    const float S2 = ws2[0] + ws2[1];
    const float mu = S1 * (1.f / DIMC);
    const float var = S2 * (1.f / DIMC) - mu * mu;
    const float rstd = rsqrtf(var + 1e-5f);
    out[(size_t)n * DIMC + t] = (y - mu) * rstd * gamma[t] + beta[t];
}

extern "C" void kernel_launch(void* const* d_in, const int* in_sizes, int n_in,
                              void* d_out, int out_size, void* d_ws, size_t ws_size,
                              hipStream_t stream)
{
    const float* x       = (const float*)d_in[0];
    const float* W       = (const float*)d_in[1];
    const float* bias    = (const float*)d_in[2];
    const float* att_src = (const float*)d_in[3];
    const float* att_dst = (const float*)d_in[4];
    const float* gamma   = (const float*)d_in[5];
    const float* beta    = (const float*)d_in[6];
    const int*   ei      = (const int*)d_in[7];   // [2][E]: row0=src, row1=dst

    const int N = in_sizes[0] / DIMC;
    const int E = in_sizes[7] / 2;

    // workspace layout
    unsigned short* hb = (unsigned short*)d_ws;               // N*128 bf16
    float* a_s   = (float*)(hb + (size_t)N * DIMC);           // N*4
    float* a_d   = a_s + (size_t)N * HEADSC;                  // N*4
    int* counts  = (int*)(a_d + (size_t)N * HEADSC);          // N
    int* offsets = counts + N;                                // N+1
    int* cursor  = offsets + N + 1;                           // N
    int* partial = cursor + N;                                // <=256
    int* rec     = partial + 256;                             // E+N

    hipMemsetAsync(counts, 0, sizeof(int) * (size_t)N, stream);

    const int nstrip = (N + 15) / 16;
    gemm_kernel<<<784, 256, 0, stream>>>(x, W, hb, N, nstrip);
    attn_kernel<<<N, 128, 0, stream>>>(hb, att_src, att_dst, a_s, a_d);
    hist_kernel<<<1024, 256, 0, stream>>>(ei + E, E, counts);
    const int nb1 = (N + 255) / 256;
    scan1_kernel<<<nb1, 256, 0, stream>>>(counts, partial, N);
    scan2_kernel<<<1, 256, 0, stream>>>(partial, offsets, nb1, N);
    scan3_kernel<<<nb1, 256, 0, stream>>>(counts, partial, offsets, cursor, N);
    scatter_kernel<<<1024, 256, 0, stream>>>(ei, E, N, cursor, rec);
    node_kernel<<<N, 128, 0, stream>>>(
        x, hb, a_s, a_d, offsets, rec, bias, gamma, beta, (float*)d_out);
}

// Round 3
// 259.241 us; speedup vs baseline: 1.5896x; 1.0697x over previous
//
#include <hip/hip_runtime.h>
#include <math.h>

#define DIMC 128
#define HEADSC 4

typedef __attribute__((ext_vector_type(8))) short bf16x8;
typedef __attribute__((ext_vector_type(4))) float f32x4;
typedef __attribute__((ext_vector_type(2))) float f32x2;

static __device__ __forceinline__ float bf2f(unsigned short u) {
    unsigned v = ((unsigned)u) << 16;
    return __builtin_bit_cast(float, v);
}
static __device__ __forceinline__ short f2bf(float f) {
    unsigned u = __builtin_bit_cast(unsigned, f);
    unsigned r = (u + 0x7fff + ((u >> 16) & 1)) >> 16;   // RNE
    return (short)r;
}

// ---------------- GEMM: h = x @ W via bf16 MFMA, h stored bf16 ----------------
__global__ __launch_bounds__(256) void gemm_kernel(
    const float* __restrict__ x, const float* __restrict__ W,
    unsigned short* __restrict__ hb, int N, int nstrip)
{
    const int lane = threadIdx.x & 63;
    const int wv   = threadIdx.x >> 6;   // 0..3
    const int pr   = wv >> 1;            // strip-pair 0/1
    const int half = wv & 1;             // column half
    const int l15  = lane & 15;
    const int lg   = lane >> 4;          // 0..3

    bf16x8 bfr[4][4];
#pragma unroll
    for (int ct = 0; ct < 4; ++ct) {
#pragma unroll
        for (int kk = 0; kk < 4; ++kk) {
            const float* wp = W + (size_t)(kk * 32 + lg * 8) * DIMC + half * 64 + ct * 16 + l15;
#pragma unroll
            for (int jj = 0; jj < 8; ++jj)
                bfr[ct][kk][jj] = f2bf(wp[(size_t)jj * DIMC]);
        }
    }

    for (int s = blockIdx.x * 2 + pr; s < nstrip; s += gridDim.x * 2) {
        const int row = s * 16 + l15;
        const float* xp = x + (size_t)row * DIMC + lg * 8;
        bf16x8 afr[4];
#pragma unroll
        for (int kk = 0; kk < 4; ++kk) {
            f32x4 v0 = *(const f32x4*)(xp + kk * 32);
            f32x4 v1 = *(const f32x4*)(xp + kk * 32 + 4);
#pragma unroll
            for (int jj = 0; jj < 4; ++jj) {
                afr[kk][jj]     = f2bf(v0[jj]);
                afr[kk][jj + 4] = f2bf(v1[jj]);
            }
        }
        f32x4 acc[4] = {};
#pragma unroll
        for (int ct = 0; ct < 4; ++ct) {
#pragma unroll
            for (int kk = 0; kk < 4; ++kk)
                acc[ct] = __builtin_amdgcn_mfma_f32_16x16x32_bf16(
                    afr[kk], bfr[ct][kk], acc[ct], 0, 0, 0);
        }
        unsigned short* hp = hb + (size_t)(s * 16) * DIMC + half * 64;
#pragma unroll
        for (int ct = 0; ct < 4; ++ct)
#pragma unroll
            for (int reg = 0; reg < 4; ++reg)
                hp[(size_t)(lg * 4 + reg) * DIMC + ct * 16 + l15] =
                    (unsigned short)f2bf(acc[ct][reg]);
    }
}

// ---------------- per-node attention logits (grid-stride) ----------------
__global__ __launch_bounds__(256) void attn_kernel(
    const unsigned short* __restrict__ hb,
    const float* __restrict__ att_src, const float* __restrict__ att_dst,
    float* __restrict__ a_s, float* __restrict__ a_d, int N)
{
    const int half = threadIdx.x >> 7;   // node sub-block 0/1
    const int t = threadIdx.x & 127;
    const float as = att_src[t];
    const float ad = att_dst[t];
    for (int n = blockIdx.x * 2 + half; n < N; n += gridDim.x * 2) {
        const float hv = bf2f(hb[(size_t)n * DIMC + t]);
        float ps = hv * as;
        float pd = hv * ad;
#pragma unroll
        for (int mk = 1; mk < 32; mk <<= 1) {
            ps += __shfl_xor(ps, mk);
            pd += __shfl_xor(pd, mk);
        }
        if ((t & 31) == 0) {
            a_s[n * HEADSC + (t >> 5)] = ps;
            a_d[n * HEADSC + (t >> 5)] = pd;
        }
    }
}

// ---------------- in-degree histogram ----------------
__global__ void hist_kernel(const int* __restrict__ dst, int E, int* __restrict__ counts)
{
    int i = blockIdx.x * blockDim.x + threadIdx.x;
    int stride = gridDim.x * blockDim.x;
    for (; i < E; i += stride) atomicAdd(&counts[dst[i]], 1);
}

// ---------------- 3-phase exclusive scan over (counts[i]+1) ----------------
__global__ __launch_bounds__(256) void scan1_kernel(
    const int* __restrict__ counts, int* __restrict__ partial, int N)
{
    const int t = threadIdx.x, i = blockIdx.x * 256 + t;
    int v = (i < N) ? counts[i] + 1 : 0;
    int s = v;
#pragma unroll
    for (int mk = 1; mk < 64; mk <<= 1) s += __shfl_xor(s, mk);
    __shared__ int ws[4];
    if ((t & 63) == 0) ws[t >> 6] = s;
    __syncthreads();
    if (t == 0) partial[blockIdx.x] = ws[0] + ws[1] + ws[2] + ws[3];
}

__global__ __launch_bounds__(256) void scan2_kernel(
    int* __restrict__ partial, int* __restrict__ offsets, int P, int N)
{
    const int t = threadIdx.x;
    const int lane = t & 63, wv = t >> 6;
    int v = (t < P) ? partial[t] : 0;
    int xs = v;
#pragma unroll
    for (int d = 1; d < 64; d <<= 1) {
        int tt = __shfl_up(xs, d);
        if (lane >= d) xs += tt;
    }
    __shared__ int ws[4], wo[4];
    if (lane == 63) ws[wv] = xs;
    __syncthreads();
    if (t == 0) {
        int s = 0;
        for (int w = 0; w < 4; ++w) { wo[w] = s; s += ws[w]; }
        offsets[N] = s;
    }
    __syncthreads();
    if (t < P) partial[t] = wo[wv] + xs - v;
}

__global__ __launch_bounds__(256) void scan3_kernel(
    const int* __restrict__ counts, const int* __restrict__ partial,
    int* __restrict__ offsets, int* __restrict__ cursor, int N)
{
    const int t = threadIdx.x, i = blockIdx.x * 256 + t;
    const int lane = t & 63, wv = t >> 6;
    int v = (i < N) ? counts[i] + 1 : 0;
    int xs = v;
#pragma unroll
    for (int d = 1; d < 64; d <<= 1) {
        int tt = __shfl_up(xs, d);
        if (lane >= d) xs += tt;
    }
    __shared__ int ws[4], wo[4];
    if (lane == 63) ws[wv] = xs;
    __syncthreads();
    if (t == 0) {
        int s = 0;
        for (int w = 0; w < 4; ++w) { wo[w] = s; s += ws[w]; }
    }
    __syncthreads();
    const int excl = partial[blockIdx.x] + wo[wv] + xs - v;
    if (i < N) { offsets[i] = excl; cursor[i] = excl; }
}

// ---------------- CSR scatter + per-edge exp(leakyrelu(logit)) ----------------
__global__ void scatter_kernel(const int* __restrict__ ei, int E, int N,
                               const float* __restrict__ a_s,
                               const float* __restrict__ a_d,
                               int* __restrict__ cursor, int* __restrict__ rec,
                               float* __restrict__ pexp)
{
    int i = blockIdx.x * blockDim.x + threadIdx.x;
    const int total = E + N;
    const int stride = gridDim.x * blockDim.x;
    for (; i < total; i += stride) {
        int s, d;
        if (i < E) { s = ei[i]; d = ei[E + i]; }
        else       { s = i - E; d = s; }
        const int pos = atomicAdd(&cursor[d], 1);
        rec[pos] = s;
        const f32x4 as = *(const f32x4*)(a_s + (size_t)s * HEADSC);
        const f32x4 ad = *(const f32x4*)(a_d + (size_t)d * HEADSC);
        f32x4 p;
#pragma unroll
        for (int h = 0; h < HEADSC; ++h) {
            float e = as[h] + ad[h];
            e = (e > 0.f) ? e : 0.2f * e;              // leaky relu
            p[h] = __expf(e);                           // no max-subtract: |e| small
        }
        *(f32x4*)(pexp + (size_t)pos * HEADSC) = p;
    }
}

// ---------------- per-node aggregate + bias + GELU + residual + LN ----------------
// 1 wave per node, 2 adjacent channels per lane. No LDS, no barriers, no exp.
__global__ __launch_bounds__(256) void node_kernel(
    const float* __restrict__ x, const unsigned short* __restrict__ hb,
    const int* __restrict__ offsets, const int* __restrict__ rec,
    const float* __restrict__ pexp,
    const float* __restrict__ bias, const float* __restrict__ gamma,
    const float* __restrict__ beta, float* __restrict__ out, int N)
{
    const int wv = threadIdx.x >> 6;         // wave in block: 0..3
    const int lane = threadIdx.x & 63;
    const int c2 = lane * 2;                 // channel pair base
    const int head = lane >> 4;              // = (2*lane)>>5

    for (int n = blockIdx.x * 4 + wv; n < N; n += gridDim.x * 4) {
        const int beg = offsets[n], end = offsets[n + 1];
        float den = 0.f, acc0 = 0.f, acc1 = 0.f;
        for (int i = beg; i < end; ++i) {
            const int s = rec[i];                            // wave-broadcast
            const float p = pexp[(size_t)i * HEADSC + head]; // head-broadcast
            den += p;
            const unsigned hv = *(const unsigned*)(hb + (size_t)s * DIMC + c2);
            const float h0 = __builtin_bit_cast(float, hv << 16);
            const float h1 = __builtin_bit_cast(float, hv & 0xffff0000u);
            acc0 = fmaf(p, h0, acc0);
            acc1 = fmaf(p, h1, acc1);
        }
        const float inv = 1.f / (den + 1e-16f);
        const f32x2 bi = *(const f32x2*)(bias + c2);
        float g0 = acc0 * inv + bi.x;
        float g1 = acc1 * inv + bi.y;
        const float ge0 = 0.5f * g0 * (1.f + erff(g0 * 0.70710678118654752f));
        const float ge1 = 0.5f * g1 * (1.f + erff(g1 * 0.70710678118654752f));
        const f32x2 xv = *(const f32x2*)(x + (size_t)n * DIMC + c2);
        const float y0 = xv.x + ge0;
        const float y1 = xv.y + ge1;
        float s1 = y0 + y1, s2 = y0 * y0 + y1 * y1;
#pragma unroll
        for (int mk = 1; mk < 64; mk <<= 1) {
            s1 += __shfl_xor(s1, mk);
            s2 += __shfl_xor(s2, mk);
        }
        const float mu = s1 * (1.f / DIMC);
        const float var = s2 * (1.f / DIMC) - mu * mu;
        const float rstd = rsqrtf(var + 1e-5f);
        const f32x2 ga = *(const f32x2*)(gamma + c2);
        const f32x2 be = *(const f32x2*)(beta + c2);
        f32x2 o;
        o.x = (y0 - mu) * rstd * ga.x + be.x;
        o.y = (y1 - mu) * rstd * ga.y + be.y;
        *(f32x2*)(out + (size_t)n * DIMC + c2) = o;
    }
}

extern "C" void kernel_launch(void* const* d_in, const int* in_sizes, int n_in,
                              void* d_out, int out_size, void* d_ws, size_t ws_size,
                              hipStream_t stream)
{
    const float* x       = (const float*)d_in[0];
    const float* W       = (const float*)d_in[1];
    const float* bias    = (const float*)d_in[2];
    const float* att_src = (const float*)d_in[3];
    const float* att_dst = (const float*)d_in[4];
    const float* gamma   = (const float*)d_in[5];
    const float* beta    = (const float*)d_in[6];
    const int*   ei      = (const int*)d_in[7];   // [2][E]: row0=src, row1=dst

    const int N = in_sizes[0] / DIMC;
    const int E = in_sizes[7] / 2;

    // workspace layout (16B-aligned sections)
    unsigned short* hb = (unsigned short*)d_ws;               // N*128 bf16
    float* a_s   = (float*)(hb + (size_t)N * DIMC);           // N*4
    float* a_d   = a_s + (size_t)N * HEADSC;                  // N*4
    float* pexp  = a_d + (size_t)N * HEADSC;                  // (E+N)*4
    int* counts  = (int*)(pexp + (size_t)(E + N) * HEADSC);   // N
    int* offsets = counts + N;                                // N+1
    int* cursor  = offsets + N + 1;                           // N
    int* partial = cursor + N;                                // <=256
    int* rec     = partial + 256;                             // E+N

    hipMemsetAsync(counts, 0, sizeof(int) * (size_t)N, stream);

    const int nstrip = (N + 15) / 16;
    gemm_kernel<<<784, 256, 0, stream>>>(x, W, hb, N, nstrip);
    attn_kernel<<<2048, 256, 0, stream>>>(hb, att_src, att_dst, a_s, a_d, N);
    hist_kernel<<<1024, 256, 0, stream>>>(ei + E, E, counts);
    const int nb1 = (N + 255) / 256;
    scan1_kernel<<<nb1, 256, 0, stream>>>(counts, partial, N);
    scan2_kernel<<<1, 256, 0, stream>>>(partial, offsets, nb1, N);
    scan3_kernel<<<nb1, 256, 0, stream>>>(counts, partial, offsets, cursor, N);
    scatter_kernel<<<1024, 256, 0, stream>>>(ei, E, N, a_s, a_d, cursor, rec, pexp);
    node_kernel<<<(N + 3) / 4, 256, 0, stream>>>(
        x, hb, offsets, rec, pexp, bias, gamma, beta, (float*)d_out, N);
}

// Round 4
// 205.270 us; speedup vs baseline: 2.0075x; 1.2629x over previous
//
#include <hip/hip_runtime.h>
#include <math.h>

#define DIMC 128
#define HEADSC 4

typedef __attribute__((ext_vector_type(8))) short bf16x8;
typedef __attribute__((ext_vector_type(4))) float f32x4;
typedef __attribute__((ext_vector_type(2))) float f32x2;

static __device__ __forceinline__ float bf2f(unsigned short u) {
    unsigned v = ((unsigned)u) << 16;
    return __builtin_bit_cast(float, v);
}
static __device__ __forceinline__ short f2bf(float f) {
    unsigned u = __builtin_bit_cast(unsigned, f);
    unsigned r = (u + 0x7fff + ((u >> 16) & 1)) >> 16;   // RNE
    return (short)r;
}
static __device__ __forceinline__ float blo(unsigned q) {
    return __builtin_bit_cast(float, q << 16);
}
static __device__ __forceinline__ float bhi(unsigned q) {
    return __builtin_bit_cast(float, q & 0xffff0000u);
}

// ------- GEMM: h = x @ W (bf16 MFMA) + fused attn logits + counts zeroing -------
__global__ __launch_bounds__(256) void gemm_kernel(
    const float* __restrict__ x, const float* __restrict__ W,
    const float* __restrict__ att_src, const float* __restrict__ att_dst,
    unsigned short* __restrict__ hb, float* __restrict__ a_s, float* __restrict__ a_d,
    int* __restrict__ counts, int N, int nstrip)
{
    // zero in-degree counters for the downstream histogram (replaces memset)
    for (int idx = blockIdx.x * 256 + threadIdx.x; idx < N; idx += gridDim.x * 256)
        counts[idx] = 0;

    const int lane = threadIdx.x & 63;
    const int wv   = threadIdx.x >> 6;   // 0..3
    const int pr   = wv >> 1;            // strip-pair 0/1
    const int half = wv & 1;             // column half
    const int l15  = lane & 15;
    const int lg   = lane >> 4;          // 0..3

    bf16x8 bfr[4][4];
#pragma unroll
    for (int ct = 0; ct < 4; ++ct) {
#pragma unroll
        for (int kk = 0; kk < 4; ++kk) {
            const float* wp = W + (size_t)(kk * 32 + lg * 8) * DIMC + half * 64 + ct * 16 + l15;
#pragma unroll
            for (int jj = 0; jj < 8; ++jj)
                bfr[ct][kk][jj] = f2bf(wp[(size_t)jj * DIMC]);
        }
    }
    // attn vectors for this lane's columns (col = half*64 + ct*16 + l15)
    float attS[4], attD[4];
#pragma unroll
    for (int ct = 0; ct < 4; ++ct) {
        attS[ct] = att_src[half * 64 + ct * 16 + l15];
        attD[ct] = att_dst[half * 64 + ct * 16 + l15];
    }

    for (int s = blockIdx.x * 2 + pr; s < nstrip; s += gridDim.x * 2) {
        const int row = s * 16 + l15;
        const float* xp = x + (size_t)row * DIMC + lg * 8;
        bf16x8 afr[4];
#pragma unroll
        for (int kk = 0; kk < 4; ++kk) {
            f32x4 v0 = *(const f32x4*)(xp + kk * 32);
            f32x4 v1 = *(const f32x4*)(xp + kk * 32 + 4);
#pragma unroll
            for (int jj = 0; jj < 4; ++jj) {
                afr[kk][jj]     = f2bf(v0[jj]);
                afr[kk][jj + 4] = f2bf(v1[jj]);
            }
        }
        f32x4 acc[4] = {};
#pragma unroll
        for (int ct = 0; ct < 4; ++ct) {
#pragma unroll
            for (int kk = 0; kk < 4; ++kk)
                acc[ct] = __builtin_amdgcn_mfma_f32_16x16x32_bf16(
                    afr[kk], bfr[ct][kk], acc[ct], 0, 0, 0);
        }
        // store h tile (bf16)
        unsigned short* hp = hb + (size_t)(s * 16) * DIMC + half * 64;
#pragma unroll
        for (int ct = 0; ct < 4; ++ct)
#pragma unroll
            for (int reg = 0; reg < 4; ++reg)
                hp[(size_t)(lg * 4 + reg) * DIMC + ct * 16 + l15] =
                    (unsigned short)f2bf(acc[ct][reg]);
        // fused attn logits: head 2*half covers ct 0,1; head 2*half+1 covers ct 2,3
#pragma unroll
        for (int reg = 0; reg < 4; ++reg) {
            float s0 = fmaf(acc[0][reg], attS[0], acc[1][reg] * attS[1]);
            float s1 = fmaf(acc[2][reg], attS[2], acc[3][reg] * attS[3]);
            float d0 = fmaf(acc[0][reg], attD[0], acc[1][reg] * attD[1]);
            float d1 = fmaf(acc[2][reg], attD[2], acc[3][reg] * attD[3]);
#pragma unroll
            for (int mk = 1; mk < 16; mk <<= 1) {
                s0 += __shfl_xor(s0, mk);
                s1 += __shfl_xor(s1, mk);
                d0 += __shfl_xor(d0, mk);
                d1 += __shfl_xor(d1, mk);
            }
            if (l15 == 0) {
                const int r = s * 16 + lg * 4 + reg;
                a_s[r * HEADSC + half * 2 + 0] = s0;
                a_s[r * HEADSC + half * 2 + 1] = s1;
                a_d[r * HEADSC + half * 2 + 0] = d0;
                a_d[r * HEADSC + half * 2 + 1] = d1;
            }
        }
    }
}

// ---------------- in-degree histogram ----------------
__global__ void hist_kernel(const int* __restrict__ dst, int E, int* __restrict__ counts)
{
    int i = blockIdx.x * blockDim.x + threadIdx.x;
    int stride = gridDim.x * blockDim.x;
    for (; i < E; i += stride) atomicAdd(&counts[dst[i]], 1);
}

// ---------------- 3-phase exclusive scan over (counts[i]+1) ----------------
__global__ __launch_bounds__(256) void scan1_kernel(
    const int* __restrict__ counts, int* __restrict__ partial, int N)
{
    const int t = threadIdx.x, i = blockIdx.x * 256 + t;
    int v = (i < N) ? counts[i] + 1 : 0;
    int s = v;
#pragma unroll
    for (int mk = 1; mk < 64; mk <<= 1) s += __shfl_xor(s, mk);
    __shared__ int ws[4];
    if ((t & 63) == 0) ws[t >> 6] = s;
    __syncthreads();
    if (t == 0) partial[blockIdx.x] = ws[0] + ws[1] + ws[2] + ws[3];
}

__global__ __launch_bounds__(256) void scan2_kernel(
    int* __restrict__ partial, int* __restrict__ offsets, int P, int N)
{
    const int t = threadIdx.x;
    const int lane = t & 63, wv = t >> 6;
    int v = (t < P) ? partial[t] : 0;
    int xs = v;
#pragma unroll
    for (int d = 1; d < 64; d <<= 1) {
        int tt = __shfl_up(xs, d);
        if (lane >= d) xs += tt;
    }
    __shared__ int ws[4], wo[4];
    if (lane == 63) ws[wv] = xs;
    __syncthreads();
    if (t == 0) {
        int s = 0;
        for (int w = 0; w < 4; ++w) { wo[w] = s; s += ws[w]; }
        offsets[N] = s;
    }
    __syncthreads();
    if (t < P) partial[t] = wo[wv] + xs - v;
}

__global__ __launch_bounds__(256) void scan3_kernel(
    const int* __restrict__ counts, const int* __restrict__ partial,
    int* __restrict__ offsets, int* __restrict__ cursor, int N)
{
    const int t = threadIdx.x, i = blockIdx.x * 256 + t;
    const int lane = t & 63, wv = t >> 6;
    int v = (i < N) ? counts[i] + 1 : 0;
    int xs = v;
#pragma unroll
    for (int d = 1; d < 64; d <<= 1) {
        int tt = __shfl_up(xs, d);
        if (lane >= d) xs += tt;
    }
    __shared__ int ws[4], wo[4];
    if (lane == 63) ws[wv] = xs;
    __syncthreads();
    if (t == 0) {
        int s = 0;
        for (int w = 0; w < 4; ++w) { wo[w] = s; s += ws[w]; }
    }
    __syncthreads();
    const int excl = partial[blockIdx.x] + wo[wv] + xs - v;
    if (i < N) { offsets[i] = excl; cursor[i] = excl; }
}

// ---------------- CSR scatter + per-edge exp(leakyrelu(logit)) ----------------
__global__ void scatter_kernel(const int* __restrict__ ei, int E, int N,
                               const float* __restrict__ a_s,
                               const float* __restrict__ a_d,
                               int* __restrict__ cursor, int* __restrict__ rec,
                               float* __restrict__ pexp)
{
    int i = blockIdx.x * blockDim.x + threadIdx.x;
    const int total = E + N;
    const int stride = gridDim.x * blockDim.x;
    for (; i < total; i += stride) {
        int s, d;
        if (i < E) { s = ei[i]; d = ei[E + i]; }
        else       { s = i - E; d = s; }
        const int pos = atomicAdd(&cursor[d], 1);
        rec[pos] = s;
        const f32x4 as = *(const f32x4*)(a_s + (size_t)s * HEADSC);
        const f32x4 ad = *(const f32x4*)(a_d + (size_t)d * HEADSC);
        f32x4 p;
#pragma unroll
        for (int h = 0; h < HEADSC; ++h) {
            float e = as[h] + ad[h];
            e = (e > 0.f) ? e : 0.2f * e;              // leaky relu
            p[h] = __expf(e);                           // no max-subtract: |e| small
        }
        *(f32x4*)(pexp + (size_t)pos * HEADSC) = p;
    }
}

// ---------------- per-node aggregate + bias + GELU + residual + LN ----------------
// 1 wave per node, 2 channels per lane, 4x-unrolled gather loop (4 in flight).
__global__ __launch_bounds__(256) void node_kernel(
    const float* __restrict__ x, const unsigned short* __restrict__ hb,
    const int* __restrict__ offsets, const int* __restrict__ rec,
    const float* __restrict__ pexp,
    const float* __restrict__ bias, const float* __restrict__ gamma,
    const float* __restrict__ beta, float* __restrict__ out, int N)
{
    const int wv = threadIdx.x >> 6;
    const int lane = threadIdx.x & 63;
    const int c2 = lane * 2;
    const int head = lane >> 4;

    for (int n = blockIdx.x * 4 + wv; n < N; n += gridDim.x * 4) {
        const int beg = __builtin_amdgcn_readfirstlane(offsets[n]);
        const int end = __builtin_amdgcn_readfirstlane(offsets[n + 1]);
        float den = 0.f, e0 = 0.f, e1 = 0.f, o0 = 0.f, o1 = 0.f;
        int i = beg;
        const int e4 = beg + ((end - beg) & ~3);
        for (; i < e4; i += 4) {
            const int s0 = rec[i + 0], s1 = rec[i + 1];
            const int s2 = rec[i + 2], s3 = rec[i + 3];
            const float p0 = pexp[(size_t)(i + 0) * HEADSC + head];
            const float p1 = pexp[(size_t)(i + 1) * HEADSC + head];
            const float p2 = pexp[(size_t)(i + 2) * HEADSC + head];
            const float p3 = pexp[(size_t)(i + 3) * HEADSC + head];
            const unsigned q0 = *(const unsigned*)(hb + (size_t)s0 * DIMC + c2);
            const unsigned q1 = *(const unsigned*)(hb + (size_t)s1 * DIMC + c2);
            const unsigned q2 = *(const unsigned*)(hb + (size_t)s2 * DIMC + c2);
            const unsigned q3 = *(const unsigned*)(hb + (size_t)s3 * DIMC + c2);
            den += (p0 + p1) + (p2 + p3);
            e0 = fmaf(p0, blo(q0), e0); e1 = fmaf(p0, bhi(q0), e1);
            o0 = fmaf(p1, blo(q1), o0); o1 = fmaf(p1, bhi(q1), o1);
            e0 = fmaf(p2, blo(q2), e0); e1 = fmaf(p2, bhi(q2), e1);
            o0 = fmaf(p3, blo(q3), o0); o1 = fmaf(p3, bhi(q3), o1);
        }
        for (; i < end; ++i) {
            const int s0 = rec[i];
            const float p0 = pexp[(size_t)i * HEADSC + head];
            const unsigned q0 = *(const unsigned*)(hb + (size_t)s0 * DIMC + c2);
            den += p0;
            e0 = fmaf(p0, blo(q0), e0);
            e1 = fmaf(p0, bhi(q0), e1);
        }
        const float acc0 = e0 + o0, acc1 = e1 + o1;

        const float inv = 1.f / (den + 1e-16f);
        const f32x2 bi = *(const f32x2*)(bias + c2);
        float g0 = acc0 * inv + bi.x;
        float g1 = acc1 * inv + bi.y;
        const float ge0 = 0.5f * g0 * (1.f + erff(g0 * 0.70710678118654752f));
        const float ge1 = 0.5f * g1 * (1.f + erff(g1 * 0.70710678118654752f));
        const f32x2 xv = *(const f32x2*)(x + (size_t)n * DIMC + c2);
        const float y0 = xv.x + ge0;
        const float y1 = xv.y + ge1;
        float s1 = y0 + y1, s2 = y0 * y0 + y1 * y1;
#pragma unroll
        for (int mk = 1; mk < 64; mk <<= 1) {
            s1 += __shfl_xor(s1, mk);
            s2 += __shfl_xor(s2, mk);
        }
        const float mu = s1 * (1.f / DIMC);
        const float var = s2 * (1.f / DIMC) - mu * mu;
        const float rstd = rsqrtf(var + 1e-5f);
        const f32x2 ga = *(const f32x2*)(gamma + c2);
        const f32x2 be = *(const f32x2*)(beta + c2);
        f32x2 o;
        o.x = (y0 - mu) * rstd * ga.x + be.x;
        o.y = (y1 - mu) * rstd * ga.y + be.y;
        *(f32x2*)(out + (size_t)n * DIMC + c2) = o;
    }
}

extern "C" void kernel_launch(void* const* d_in, const int* in_sizes, int n_in,
                              void* d_out, int out_size, void* d_ws, size_t ws_size,
                              hipStream_t stream)
{
    const float* x       = (const float*)d_in[0];
    const float* W       = (const float*)d_in[1];
    const float* bias    = (const float*)d_in[2];
    const float* att_src = (const float*)d_in[3];
    const float* att_dst = (const float*)d_in[4];
    const float* gamma   = (const float*)d_in[5];
    const float* beta    = (const float*)d_in[6];
    const int*   ei      = (const int*)d_in[7];   // [2][E]: row0=src, row1=dst

    const int N = in_sizes[0] / DIMC;
    const int E = in_sizes[7] / 2;

    // workspace layout (16B-aligned sections)
    unsigned short* hb = (unsigned short*)d_ws;               // N*128 bf16
    float* a_s   = (float*)(hb + (size_t)N * DIMC);           // N*4
    float* a_d   = a_s + (size_t)N * HEADSC;                  // N*4
    float* pexp  = a_d + (size_t)N * HEADSC;                  // (E+N)*4
    int* counts  = (int*)(pexp + (size_t)(E + N) * HEADSC);   // N
    int* offsets = counts + N;                                // N+1
    int* cursor  = offsets + N + 1;                           // N
    int* partial = cursor + N;                                // <=256
    int* rec     = partial + 256;                             // E+N

    const int nstrip = (N + 15) / 16;
    gemm_kernel<<<784, 256, 0, stream>>>(x, W, att_src, att_dst, hb, a_s, a_d,
                                         counts, N, nstrip);
    hist_kernel<<<2048, 256, 0, stream>>>(ei + E, E, counts);
    const int nb1 = (N + 255) / 256;
    scan1_kernel<<<nb1, 256, 0, stream>>>(counts, partial, N);
    scan2_kernel<<<1, 256, 0, stream>>>(partial, offsets, nb1, N);
    scan3_kernel<<<nb1, 256, 0, stream>>>(counts, partial, offsets, cursor, N);
    scatter_kernel<<<2048, 256, 0, stream>>>(ei, E, N, a_s, a_d, cursor, rec, pexp);
    node_kernel<<<(N + 3) / 4, 256, 0, stream>>>(
        x, hb, offsets, rec, pexp, bias, gamma, beta, (float*)d_out, N);
}

// Round 5
// 200.191 us; speedup vs baseline: 2.0585x; 1.0254x over previous
//
#include <hip/hip_runtime.h>
#include <math.h>

#define DIMC 128
#define HEADSC 4

typedef __attribute__((ext_vector_type(8))) short bf16x8;
typedef __attribute__((ext_vector_type(4))) float f32x4;
typedef __attribute__((ext_vector_type(2))) float f32x2;

static __device__ __forceinline__ short f2bf(float f) {
    unsigned u = __builtin_bit_cast(unsigned, f);
    unsigned r = (u + 0x7fff + ((u >> 16) & 1)) >> 16;   // RNE
    return (short)r;
}
static __device__ __forceinline__ float blo(unsigned q) {
    return __builtin_bit_cast(float, q << 16);
}
static __device__ __forceinline__ float bhi(unsigned q) {
    return __builtin_bit_cast(float, q & 0xffff0000u);
}

// -- GEMM: h = x @ W (bf16 MFMA) + fused attn logits + fused edge histogram --
__global__ __launch_bounds__(256) void gemm_hist_kernel(
    const float* __restrict__ x, const float* __restrict__ W,
    const float* __restrict__ att_src, const float* __restrict__ att_dst,
    const int* __restrict__ dst, int E,
    unsigned short* __restrict__ hb, float* __restrict__ a_s, float* __restrict__ a_d,
    int* __restrict__ counts, int N, int nstrip)
{
    const int lane = threadIdx.x & 63;
    const int wv   = threadIdx.x >> 6;   // 0..3
    const int pr   = wv >> 1;            // strip-pair 0/1
    const int half = wv & 1;             // column half
    const int l15  = lane & 15;
    const int lg   = lane >> 4;          // 0..3

    bf16x8 bfr[4][4];
#pragma unroll
    for (int ct = 0; ct < 4; ++ct) {
#pragma unroll
        for (int kk = 0; kk < 4; ++kk) {
            const float* wp = W + (size_t)(kk * 32 + lg * 8) * DIMC + half * 64 + ct * 16 + l15;
#pragma unroll
            for (int jj = 0; jj < 8; ++jj)
                bfr[ct][kk][jj] = f2bf(wp[(size_t)jj * DIMC]);
        }
    }
    float attS[4], attD[4];
#pragma unroll
    for (int ct = 0; ct < 4; ++ct) {
        attS[ct] = att_src[half * 64 + ct * 16 + l15];
        attD[ct] = att_dst[half * 64 + ct * 16 + l15];
    }

    for (int s = blockIdx.x * 2 + pr; s < nstrip; s += gridDim.x * 2) {
        const int row = s * 16 + l15;
        const float* xp = x + (size_t)row * DIMC + lg * 8;
        bf16x8 afr[4];
#pragma unroll
        for (int kk = 0; kk < 4; ++kk) {
            f32x4 v0 = *(const f32x4*)(xp + kk * 32);
            f32x4 v1 = *(const f32x4*)(xp + kk * 32 + 4);
#pragma unroll
            for (int jj = 0; jj < 4; ++jj) {
                afr[kk][jj]     = f2bf(v0[jj]);
                afr[kk][jj + 4] = f2bf(v1[jj]);
            }
        }
        f32x4 acc[4] = {};
#pragma unroll
        for (int ct = 0; ct < 4; ++ct) {
#pragma unroll
            for (int kk = 0; kk < 4; ++kk)
                acc[ct] = __builtin_amdgcn_mfma_f32_16x16x32_bf16(
                    afr[kk], bfr[ct][kk], acc[ct], 0, 0, 0);
        }
        unsigned short* hp = hb + (size_t)(s * 16) * DIMC + half * 64;
#pragma unroll
        for (int ct = 0; ct < 4; ++ct)
#pragma unroll
            for (int reg = 0; reg < 4; ++reg)
                hp[(size_t)(lg * 4 + reg) * DIMC + ct * 16 + l15] =
                    (unsigned short)f2bf(acc[ct][reg]);
#pragma unroll
        for (int reg = 0; reg < 4; ++reg) {
            float s0 = fmaf(acc[0][reg], attS[0], acc[1][reg] * attS[1]);
            float s1 = fmaf(acc[2][reg], attS[2], acc[3][reg] * attS[3]);
            float d0 = fmaf(acc[0][reg], attD[0], acc[1][reg] * attD[1]);
            float d1 = fmaf(acc[2][reg], attD[2], acc[3][reg] * attD[3]);
#pragma unroll
            for (int mk = 1; mk < 16; mk <<= 1) {
                s0 += __shfl_xor(s0, mk);
                s1 += __shfl_xor(s1, mk);
                d0 += __shfl_xor(d0, mk);
                d1 += __shfl_xor(d1, mk);
            }
            if (l15 == 0) {
                const int r = s * 16 + lg * 4 + reg;
                a_s[r * HEADSC + half * 2 + 0] = s0;
                a_s[r * HEADSC + half * 2 + 1] = s1;
                a_d[r * HEADSC + half * 2 + 0] = d0;
                a_d[r * HEADSC + half * 2 + 1] = d1;
            }
        }
    }

    // ---- fused in-degree histogram (disjoint data; overlaps gemm memory) ----
    const int tid = blockIdx.x * 256 + threadIdx.x;
    const int stride = gridDim.x * 256;
    if (((E & 3) == 0) && ((((size_t)dst) & 15) == 0)) {
        const int E4 = E >> 2;
        for (int i = tid; i < E4; i += stride) {
            const int4 d4 = ((const int4*)dst)[i];
            atomicAdd(&counts[d4.x], 1);
            atomicAdd(&counts[d4.y], 1);
            atomicAdd(&counts[d4.z], 1);
            atomicAdd(&counts[d4.w], 1);
        }
    } else {
        for (int i = tid; i < E; i += stride) atomicAdd(&counts[dst[i]], 1);
    }
}

// ---------------- scan phase 1: per-block sums of (counts[i]+1) ----------------
__global__ __launch_bounds__(256) void scan1_kernel(
    const int* __restrict__ counts, int* __restrict__ partial, int N)
{
    const int t = threadIdx.x, i = blockIdx.x * 256 + t;
    int v = (i < N) ? counts[i] + 1 : 0;
    int s = v;
#pragma unroll
    for (int mk = 1; mk < 64; mk <<= 1) s += __shfl_xor(s, mk);
    __shared__ int ws[4];
    if ((t & 63) == 0) ws[t >> 6] = s;
    __syncthreads();
    if (t == 0) partial[blockIdx.x] = ws[0] + ws[1] + ws[2] + ws[3];
}

// ------- scan phase 2: redundant partial-scan per block + chunk scan -> S -------
// S[i] = exclusive CSR start of node i. (P <= 256 required.)
__global__ __launch_bounds__(256) void scan23_kernel(
    const int* __restrict__ counts, const int* __restrict__ partial,
    int* __restrict__ S, int N, int P)
{
    const int t = threadIdx.x;
    const int lane = t & 63, wv = t >> 6;
    __shared__ int ws[4];
    __shared__ int ex[256];

    int pv = (t < P) ? partial[t] : 0;
    int xs = pv;
#pragma unroll
    for (int d = 1; d < 64; d <<= 1) { int tt = __shfl_up(xs, d); if (lane >= d) xs += tt; }
    if (lane == 63) ws[wv] = xs;
    __syncthreads();
    int wof = 0;
#pragma unroll
    for (int w = 0; w < 4; ++w) wof += (w < wv) ? ws[w] : 0;
    ex[t] = wof + xs - pv;                    // exclusive scan of partial
    __syncthreads();
    const int prefix = ex[blockIdx.x];
    __syncthreads();

    const int i = blockIdx.x * 256 + t;
    int v = (i < N) ? counts[i] + 1 : 0;
    int s2 = v;
#pragma unroll
    for (int d = 1; d < 64; d <<= 1) { int tt = __shfl_up(s2, d); if (lane >= d) s2 += tt; }
    if (lane == 63) ws[wv] = s2;
    __syncthreads();
    int wof2 = 0;
#pragma unroll
    for (int w = 0; w < 4; ++w) wof2 += (w < wv) ? ws[w] : 0;
    if (i < N) S[i] = prefix + wof2 + s2 - v;
}

// -------- CSR scatter: rec only; S mutates to segment-end in place --------
__global__ void scatter_kernel(const int* __restrict__ ei, int E, int N,
                               int* __restrict__ S, int* __restrict__ rec)
{
    const int tid = blockIdx.x * blockDim.x + threadIdx.x;
    const int stride = gridDim.x * blockDim.x;
    if (((E & 3) == 0) && ((((size_t)ei) & 15) == 0)) {
        const int E4 = E >> 2;
        const int4* s4p = (const int4*)ei;
        const int4* d4p = (const int4*)(ei + E);
        for (int i = tid; i < E4; i += stride) {
            const int4 s4 = s4p[i];
            const int4 d4 = d4p[i];
            rec[atomicAdd(&S[d4.x], 1)] = s4.x;
            rec[atomicAdd(&S[d4.y], 1)] = s4.y;
            rec[atomicAdd(&S[d4.z], 1)] = s4.z;
            rec[atomicAdd(&S[d4.w], 1)] = s4.w;
        }
    } else {
        for (int i = tid; i < E; i += stride)
            rec[atomicAdd(&S[ei[E + i]], 1)] = ei[i];
    }
    for (int n = tid; n < N; n += stride)        // self loops
        rec[atomicAdd(&S[n], 1)] = n;
}

// ------ per-node aggregate (inline exp) + bias + GELU + residual + LN ------
// 1 wave per node, 2 channels per lane, 4x-unrolled gather loop.
__global__ __launch_bounds__(256) void node_kernel(
    const float* __restrict__ x, const unsigned short* __restrict__ hb,
    const int* __restrict__ S, const int* __restrict__ rec,
    const float* __restrict__ a_s, const float* __restrict__ a_d,
    const float* __restrict__ bias, const float* __restrict__ gamma,
    const float* __restrict__ beta, float* __restrict__ out, int N)
{
    const int wv = threadIdx.x >> 6;
    const int lane = threadIdx.x & 63;
    const int c2 = lane * 2;
    const int head = lane >> 4;

    for (int n = blockIdx.x * 4 + wv; n < N; n += gridDim.x * 4) {
        // post-scatter: S[n-1] = CSR start(n), S[n] = CSR end(n)
        const int beg = __builtin_amdgcn_readfirstlane(n ? S[n - 1] : 0);
        const int end = __builtin_amdgcn_readfirstlane(S[n]);
        const float adh = a_d[n * HEADSC + head];
        float den = 0.f, e0 = 0.f, e1 = 0.f, o0 = 0.f, o1 = 0.f;
        int i = beg;
        const int e4 = beg + ((end - beg) & ~3);
        for (; i < e4; i += 4) {
            const int s0 = rec[i + 0], s1 = rec[i + 1];
            const int s2 = rec[i + 2], s3 = rec[i + 3];
            float t0 = a_s[s0 * HEADSC + head] + adh;
            float t1 = a_s[s1 * HEADSC + head] + adh;
            float t2 = a_s[s2 * HEADSC + head] + adh;
            float t3 = a_s[s3 * HEADSC + head] + adh;
            const unsigned q0 = *(const unsigned*)(hb + (size_t)s0 * DIMC + c2);
            const unsigned q1 = *(const unsigned*)(hb + (size_t)s1 * DIMC + c2);
            const unsigned q2 = *(const unsigned*)(hb + (size_t)s2 * DIMC + c2);
            const unsigned q3 = *(const unsigned*)(hb + (size_t)s3 * DIMC + c2);
            t0 = (t0 > 0.f) ? t0 : 0.2f * t0;
            t1 = (t1 > 0.f) ? t1 : 0.2f * t1;
            t2 = (t2 > 0.f) ? t2 : 0.2f * t2;
            t3 = (t3 > 0.f) ? t3 : 0.2f * t3;
            const float p0 = __expf(t0), p1 = __expf(t1);
            const float p2 = __expf(t2), p3 = __expf(t3);
            den += (p0 + p1) + (p2 + p3);
            e0 = fmaf(p0, blo(q0), e0); e1 = fmaf(p0, bhi(q0), e1);
            o0 = fmaf(p1, blo(q1), o0); o1 = fmaf(p1, bhi(q1), o1);
            e0 = fmaf(p2, blo(q2), e0); e1 = fmaf(p2, bhi(q2), e1);
            o0 = fmaf(p3, blo(q3), o0); o1 = fmaf(p3, bhi(q3), o1);
        }
        for (; i < end; ++i) {
            const int s0 = rec[i];
            float t0 = a_s[s0 * HEADSC + head] + adh;
            const unsigned q0 = *(const unsigned*)(hb + (size_t)s0 * DIMC + c2);
            t0 = (t0 > 0.f) ? t0 : 0.2f * t0;
            const float p0 = __expf(t0);
            den += p0;
            e0 = fmaf(p0, blo(q0), e0);
            e1 = fmaf(p0, bhi(q0), e1);
        }
        const float acc0 = e0 + o0, acc1 = e1 + o1;

        const float inv = 1.f / (den + 1e-16f);
        const f32x2 bi = *(const f32x2*)(bias + c2);
        float g0 = acc0 * inv + bi.x;
        float g1 = acc1 * inv + bi.y;
        const float ge0 = 0.5f * g0 * (1.f + erff(g0 * 0.70710678118654752f));
        const float ge1 = 0.5f * g1 * (1.f + erff(g1 * 0.70710678118654752f));
        const f32x2 xv = *(const f32x2*)(x + (size_t)n * DIMC + c2);
        const float y0 = xv.x + ge0;
        const float y1 = xv.y + ge1;
        float s1 = y0 + y1, s2 = y0 * y0 + y1 * y1;
#pragma unroll
        for (int mk = 1; mk < 64; mk <<= 1) {
            s1 += __shfl_xor(s1, mk);
            s2 += __shfl_xor(s2, mk);
        }
        const float mu = s1 * (1.f / DIMC);
        const float var = s2 * (1.f / DIMC) - mu * mu;
        const float rstd = rsqrtf(var + 1e-5f);
        const f32x2 ga = *(const f32x2*)(gamma + c2);
        const f32x2 be = *(const f32x2*)(beta + c2);
        f32x2 o;
        o.x = (y0 - mu) * rstd * ga.x + be.x;
        o.y = (y1 - mu) * rstd * ga.y + be.y;
        *(f32x2*)(out + (size_t)n * DIMC + c2) = o;
    }
}

extern "C" void kernel_launch(void* const* d_in, const int* in_sizes, int n_in,
                              void* d_out, int out_size, void* d_ws, size_t ws_size,
                              hipStream_t stream)
{
    const float* x       = (const float*)d_in[0];
    const float* W       = (const float*)d_in[1];
    const float* bias    = (const float*)d_in[2];
    const float* att_src = (const float*)d_in[3];
    const float* att_dst = (const float*)d_in[4];
    const float* gamma   = (const float*)d_in[5];
    const float* beta    = (const float*)d_in[6];
    const int*   ei      = (const int*)d_in[7];   // [2][E]: row0=src, row1=dst

    const int N = in_sizes[0] / DIMC;
    const int E = in_sizes[7] / 2;

    // workspace layout (16B-aligned sections)
    unsigned short* hb = (unsigned short*)d_ws;               // N*128 bf16
    float* a_s   = (float*)(hb + (size_t)N * DIMC);           // N*4
    float* a_d   = a_s + (size_t)N * HEADSC;                  // N*4
    int* counts  = (int*)(a_d + (size_t)N * HEADSC);          // N
    int* S       = counts + N;                                // N
    int* partial = S + N;                                     // <=256
    int* rec     = partial + 256;                             // E+N

    hipMemsetAsync(counts, 0, sizeof(int) * (size_t)N, stream);

    const int nstrip = (N + 15) / 16;
    gemm_hist_kernel<<<784, 256, 0, stream>>>(x, W, att_src, att_dst, ei + E, E,
                                              hb, a_s, a_d, counts, N, nstrip);
    const int nb1 = (N + 255) / 256;
    scan1_kernel<<<nb1, 256, 0, stream>>>(counts, partial, N);
    scan23_kernel<<<nb1, 256, 0, stream>>>(counts, partial, S, N, nb1);
    scatter_kernel<<<640, 256, 0, stream>>>(ei, E, N, S, rec);
    node_kernel<<<(N + 3) / 4, 256, 0, stream>>>(
        x, hb, S, rec, a_s, a_d, bias, gamma, beta, (float*)d_out, N);
}